// Round 3
// baseline (209.798 us; speedup 1.0000x reference)
//
#include <hip/hip_runtime.h>
#include <cstdint>

// ---------------- problem constants ----------------
constexpr int RS  = 48;    // sigma ranks
constexpr int RC  = 144;   // feature ranks
constexpr int PP  = 27;    // feats dim
constexpr int NV  = 128;   // voxels per axis
constexpr int CHN = 128;   // MLP hidden

// ---------------- ws layout (bf16 element offsets) ----------------
constexpr int SIG_E  = 0;                      // sigmaT [3][128][64]   = 24576
constexpr int FEAT_E = 24576;                  // featT  [3][128][160]  = 61440
constexpr int BF_E   = 86016;                  // B frags [5][2][64][8] = 5120
constexpr int W1_E   = 91136;                  // W1 frags [4][8][64][8]= 16384
constexpr int W2_E   = 107520;                 // W2 frags              = 16384
constexpr int W3_E   = 123904;                 // W3 frags [4][64][8]   = 2048
constexpr int TOT_E  = 125952;

typedef __attribute__((ext_vector_type(8))) short short8;
typedef __attribute__((ext_vector_type(4))) float f32x4;
typedef __attribute__((ext_vector_type(2))) unsigned int u32x2;
typedef __attribute__((ext_vector_type(4))) unsigned int u32x4;

__device__ __forceinline__ short f2bf(float f) {          // RNE (prep only)
    unsigned int u = __builtin_bit_cast(unsigned int, f);
    u += 0x7fffu + ((u >> 16) & 1u);
    return (short)(u >> 16);
}
__device__ __forceinline__ float bfu(unsigned int u) {    // bf16 bits in hi-half -> f32
    return __builtin_bit_cast(float, u);
}
// pack two floats -> 2 bf16 in one dword (compiler emits v_cvt_pk_bf16_f32)
__device__ __forceinline__ unsigned int pk2bf(float a, float b) {
    unsigned short ua = __builtin_bit_cast(unsigned short, (__bf16)a);
    unsigned short ub = __builtin_bit_cast(unsigned short, (__bf16)b);
    return (unsigned int)ua | ((unsigned int)ub << 16);
}

// ---------------- prep: build bf16 tables + fragment-layout weights ----------------
__global__ void prep_kernel(const float* __restrict__ sigma, const float* __restrict__ feature,
                            const float* __restrict__ Bm, const float* __restrict__ W1,
                            const float* __restrict__ W2, const float* __restrict__ W3,
                            short* __restrict__ ws) {
    int idx = blockIdx.x * 256 + threadIdx.x;
    if (idx >= TOT_E) return;
    float val = 0.f;
    if (idx < FEAT_E) {                         // sigmaT
        int a = idx / 8192, t = idx % 8192;
        int v = t / 64, r = t % 64;
        val = (r < RS) ? sigma[(a * RS + r) * NV + v] : 0.f;
    } else if (idx < BF_E) {                    // featT
        int j = idx - FEAT_E;
        int a = j / 20480, t = j % 20480;
        int v = t / 160, r = t % 160;
        val = (r < RC) ? feature[(a * RC + r) * NV + v] : 0.f;
    } else if (idx < W1_E) {                    // B frags
        int j = idx - BF_E;
        int frag = j >> 9, li = (j >> 3) & 63, e = j & 7;
        int kt = frag >> 1, nt = frag & 1;
        int k = kt * 32 + (li >> 4) * 8 + e;
        int n = nt * 16 + (li & 15);
        val = (k < RC && n < PP) ? Bm[k * PP + n] : 0.f;
    } else if (idx < W2_E) {                    // W1 frags, permuted rows
        int j = idx - W1_E;
        int frag = j >> 9, li = (j >> 3) & 63, e = j & 7;
        int kt = frag >> 3, nt = frag & 7;
        int kn = kt * 32 + (li >> 4) * 8 + e;   // k in interleaved order
        int n = nt * 16 + (li & 15);
        if (kn < 120) {
            int ko;
            if (kn < 108) { ko = (kn & 3) * PP + (kn >> 2); }            // feats: l*27 + c
            else { int t2 = kn - 108; ko = 108 + (t2 & 3) * 3 + (t2 >> 2); } // dirs
            val = W1[ko * CHN + n];
        }
    } else if (idx < W3_E) {                    // W2 frags
        int j = idx - W2_E;
        int frag = j >> 9, li = (j >> 3) & 63, e = j & 7;
        int kt = frag >> 3, nt = frag & 7;
        int k = kt * 32 + (li >> 4) * 8 + e;
        int n = nt * 16 + (li & 15);
        val = W2[k * CHN + n];
    } else {                                    // W3 frags
        int j = idx - W3_E;
        int frag = j >> 9, li = (j >> 3) & 63, e = j & 7;
        int kt = frag;
        int k = kt * 32 + (li >> 4) * 8 + e;
        int n = li & 15;
        val = (n < 3) ? W3[k * 3 + n] : 0.f;
    }
    ws[idx] = f2bf(val);
}

// lerp 8 ranks (4 packed dwords) with weight w, multiply into pr[]
__device__ __forceinline__ void lerp8(const short* rl, int stride, float w, float* pr, bool first) {
    u32x4 Lo = *(const u32x4*)rl;
    u32x4 Hi = *(const u32x4*)(rl + stride);
#pragma unroll
    for (int d = 0; d < 4; ++d) {
        unsigned int lw = Lo[d], hw = Hi[d];
        float fl0 = bfu(lw << 16), fl1 = bfu(lw & 0xffff0000u);
        float fh0 = bfu(hw << 16), fh1 = bfu(hw & 0xffff0000u);
        float s0 = fmaf(fh0 - fl0, w, fl0);
        float s1 = fmaf(fh1 - fl1, w, fl1);
        if (first) { pr[2 * d] = s0; pr[2 * d + 1] = s1; }
        else       { pr[2 * d] *= s0; pr[2 * d + 1] *= s1; }
    }
}

// ---------------- main fused kernel: 4 waves/block, 16 points per wave ----------------
// LDS/block: 4 x 4KB X + 1.5KB voxs = 17.9KB for 4 waves -> 9 blocks/CU -> 32 waves (cap).
// __launch_bounds__(256,8) pins VGPR <= 64 (8 waves/SIMD).
__global__ __launch_bounds__(256, 8)
void tensorf_main(const float* __restrict__ xyz, const float* __restrict__ dird,
                  const float* __restrict__ voxel,
                  const float* __restrict__ b1, const float* __restrict__ b2,
                  const float* __restrict__ b3,
                  const short* __restrict__ ws, float* __restrict__ out, int Np) {
    __shared__ float voxs[3 * NV];
    __shared__ char  X[4 * 16 * 256];  // per-wave 16 pts x 128 bf16, XOR-swizzled

    const int tid = threadIdx.x;
    const int wid = tid >> 6;
    const int lane = tid & 63;
    const int quad = lane >> 4, lane16 = lane & 15;
    const int wavebase = blockIdx.x * 64 + wid * 16;
    char* Xw = X + wid * 16 * 256;

    for (int i = tid; i < 3 * NV; i += 256) voxs[i] = voxel[i];
    __syncthreads();

    const short* SIGT  = ws + SIG_E;
    const short* FEATT = ws + FEAT_E;
    const short* BFr   = ws + BF_E;

    // ---------------- phase A: one pass of 16 points ----------------
    {
        const int p = wavebase + lane16;

        int ipb[3]; float we[3];
#pragma unroll
        for (int a = 0; a < 3; ++a) {
            float x = xyz[p * 3 + a];
            int ind = (int)ceilf(x * 127.f);
            ind = min(max(ind, 0), 128);
            while (ind > 0 && voxs[a * NV + ind - 1] >= x) --ind;   // searchsorted-left fixup
            while (ind < 128 && voxs[a * NV + ind] < x) ++ind;
            int il = min(max(ind - 1, 0), 127);
            int ir = min(ind, 127);
            float vl = voxs[a * NV + il], vr = voxs[a * NV + ir];
            float w = (x - vl) / (vr - vl + 1e-6f);
            we[a] = (il == 127) ? 1.f : w;      // il==ir==127 edge
            ipb[a] = min(il, 126);
        }

        // ---- sigma ----
        float sig = 0.f;
#pragma unroll
        for (int kt = 0; kt < 2; ++kt) {
            float pr[8];
#pragma unroll
            for (int a = 0; a < 3; ++a)
                lerp8(SIGT + (a * NV + ipb[a]) * 64 + kt * 32 + quad * 8, 64, we[a], pr, a == 0);
#pragma unroll
            for (int j = 0; j < 8; ++j) sig += pr[j];
        }
        sig += __shfl_xor(sig, 16);
        sig += __shfl_xor(sig, 32);
        if (lane < 16) out[p] = log1pf(expf(sig - 5.f));   // softplus(sig + bias)

        // ---- feats = fprod @ B via MFMA ----
        f32x4 acc0 = {0.f, 0.f, 0.f, 0.f}, acc1 = {0.f, 0.f, 0.f, 0.f};
#pragma unroll
        for (int kt = 0; kt < 5; ++kt) {
            float pr[8];
#pragma unroll
            for (int a = 0; a < 3; ++a)
                lerp8(FEATT + (a * NV + ipb[a]) * 160 + kt * 32 + quad * 8, 160, we[a], pr, a == 0);
            u32x4 uu;
#pragma unroll
            for (int d = 0; d < 4; ++d) uu[d] = pk2bf(pr[2 * d], pr[2 * d + 1]);
            short8 af = __builtin_bit_cast(short8, uu);
            short8 bf0 = *(const short8*)(BFr + ((kt * 2 + 0) * 64 + lane) * 8);
            short8 bf1 = *(const short8*)(BFr + ((kt * 2 + 1) * 64 + lane) * 8);
            acc0 = __builtin_amdgcn_mfma_f32_16x16x32_bf16(af, bf0, acc0, 0, 0, 0);
            acc1 = __builtin_amdgcn_mfma_f32_16x16x32_bf16(af, bf1, acc1, 0, 0, 0);
        }

        // ---- encode feats -> X (double-angle for the l=1 band) ----
#pragma unroll
        for (int nt = 0; nt < 2; ++nt) {
            int c = nt * 16 + lane16;
            f32x4 A = nt ? acc1 : acc0;
            if (c < PP) {
#pragma unroll
                for (int j = 0; j < 4; ++j) {
                    int row = quad * 4 + j;              // D-frag row
                    float f = A[j];
                    float s1 = __sinf(f), c1 = __cosf(f);
                    float s2 = 2.f * s1 * c1;            // sin 2f
                    float c2 = fmaf(-2.f * s1, s1, 1.f); // cos 2f
                    unsigned int w0 = pk2bf(s1, c1);
                    unsigned int w1 = pk2bf(s2, c2);
                    int byte = c * 8;
                    int chunk = byte >> 4, off = byte & 15;
                    *(u32x2*)(Xw + row * 256 + ((chunk ^ (row & 7)) << 4) + off) = u32x2{w0, w1};
                }
            }
        }
        // ---- dirs encode + zero-pad cols 120..127 ----
        {
            int row = lane16;
            if (quad < 3) {
                float d = dird[p * 3 + quad];
                float s1 = __sinf(d), c1 = __cosf(d);
                float s2 = 2.f * s1 * c1;
                float c2 = fmaf(-2.f * s1, s1, 1.f);
                unsigned int w0 = pk2bf(s1, c1);
                unsigned int w1 = pk2bf(s2, c2);
                int byte = 216 + 8 * quad;
                int chunk = byte >> 4, off = byte & 15;
                *(u32x2*)(Xw + row * 256 + ((chunk ^ (row & 7)) << 4) + off) = u32x2{w0, w1};
            } else {
                int addr = row * 256 + ((15 ^ (row & 7)) << 4);
                *(u32x4*)(Xw + addr) = u32x4{0u, 0u, 0u, 0u};
            }
        }
    }
    __syncthreads();

    // ---------------- phase B: per-wave MLP, M=16 (1 tile) ----------------
    const short* W1F = ws + W1_E;
    const short* W2F = ws + W2_E;
    const short* W3F = ws + W3_E;

#pragma unroll 1
    for (int layer = 0; layer < 2; ++layer) {
        const short* WF = layer ? W2F : W1F;
        const float* bb = layer ? b2 : b1;

        short8 af[4];
#pragma unroll
        for (int kt = 0; kt < 4; ++kt) {
            int row = lane16;
            int chunk = kt * 4 + quad;
            af[kt] = *(const short8*)(Xw + row * 256 + ((chunk ^ (row & 7)) << 4));
        }

#pragma unroll 1
        for (int nt = 0; nt < 8; ++nt) {
            short8 wf[4];
#pragma unroll
            for (int kt = 0; kt < 4; ++kt)
                wf[kt] = *(const short8*)(WF + ((kt * 8 + nt) * 64 + lane) * 8);
            f32x4 acc = {0.f, 0.f, 0.f, 0.f};
#pragma unroll
            for (int kt = 0; kt < 4; ++kt)
                acc = __builtin_amdgcn_mfma_f32_16x16x32_bf16(af[kt], wf[kt], acc, 0, 0, 0);

            float bvv = bb[nt * 16 + lane16];
#pragma unroll
            for (int j = 0; j < 4; ++j) {
                float v = acc[j] + bvv;
                v = fmaxf(v, 0.01f * v);                // leaky relu
                int row = quad * 4 + j;
                int byte = (nt * 16 + lane16) * 2;
                int chunk = byte >> 4, off = byte & 15;
                *(short*)(Xw + row * 256 + ((chunk ^ (row & 7)) << 4) + off) =
                    (short)__builtin_bit_cast(unsigned short, (__bf16)v);
            }
        }
        __syncthreads();
    }

    // ---- layer 3: 128 -> 3 (+sigmoid) ----
    {
        short8 af[4];
#pragma unroll
        for (int kt = 0; kt < 4; ++kt) {
            int row = lane16;
            int chunk = kt * 4 + quad;
            af[kt] = *(const short8*)(Xw + row * 256 + ((chunk ^ (row & 7)) << 4));
        }
        short8 wf3[4];
#pragma unroll
        for (int kt = 0; kt < 4; ++kt)
            wf3[kt] = *(const short8*)(W3F + (kt * 64 + lane) * 8);

        f32x4 acc3 = {0.f, 0.f, 0.f, 0.f};
#pragma unroll
        for (int kt = 0; kt < 4; ++kt)
            acc3 = __builtin_amdgcn_mfma_f32_16x16x32_bf16(af[kt], wf3[kt], acc3, 0, 0, 0);

        if (lane16 < 3) {
            float bvv = b3[lane16];
#pragma unroll
            for (int j = 0; j < 4; ++j) {
                float v = acc3[j] + bvv;
                float r = 1.f / (1.f + expf(-v));       // sigmoid
                int row = quad * 4 + j;
                out[Np + (wavebase + row) * 3 + lane16] = r;
            }
        }
    }
}

// ---------------- launch ----------------
extern "C" void kernel_launch(void* const* d_in, const int* in_sizes, int n_in,
                              void* d_out, int out_size, void* d_ws, size_t ws_size,
                              hipStream_t stream) {
    (void)n_in; (void)out_size; (void)ws_size;
    const float* xyz      = (const float*)d_in[0];
    const float* dird     = (const float*)d_in[1];
    const float* voxel    = (const float*)d_in[2];
    const float* sigma    = (const float*)d_in[3];
    const float* feature  = (const float*)d_in[4];
    const float* Bm       = (const float*)d_in[5];
    const float* W1       = (const float*)d_in[6];
    const float* b1       = (const float*)d_in[7];
    const float* W2       = (const float*)d_in[8];
    const float* b2       = (const float*)d_in[9];
    const float* W3       = (const float*)d_in[10];
    const float* b3       = (const float*)d_in[11];
    float* out = (float*)d_out;
    short* ws  = (short*)d_ws;

    const int Np = in_sizes[0] / 3;   // 524288

    prep_kernel<<<(TOT_E + 255) / 256, 256, 0, stream>>>(sigma, feature, Bm, W1, W2, W3, ws);
    tensorf_main<<<Np / 64, 256, 0, stream>>>(xyz, dird, voxel, b1, b2, b3, ws, out, Np);
}